// Round 2
// baseline (81.484 us; speedup 1.0000x reference)
//
#include <hip/hip_runtime.h>
#include <hip/hip_bf16.h>

// 4-qubit state: 16 complex amplitudes in registers.
// Index convention (matches reference): wire w is bit (3-w), i.e. wire 0 = MSB (weight 8).

template<int STRIDE>
__device__ __forceinline__ void ry_gate(float re[16], float im[16], float c, float s) {
    #pragma unroll
    for (int base = 0; base < 16; base += 2 * STRIDE) {
        #pragma unroll
        for (int off = 0; off < STRIDE; ++off) {
            const int i0 = base + off, i1 = i0 + STRIDE;
            const float r0 = re[i0], m0 = im[i0], r1 = re[i1], m1 = im[i1];
            re[i0] = c * r0 - s * r1;  im[i0] = c * m0 - s * m1;
            re[i1] = s * r0 + c * r1;  im[i1] = s * m0 + c * m1;
        }
    }
}

template<int STRIDE>
__device__ __forceinline__ void rx_gate(float re[16], float im[16], float c, float s) {
    // [[c, -i s], [-i s, c]]
    #pragma unroll
    for (int base = 0; base < 16; base += 2 * STRIDE) {
        #pragma unroll
        for (int off = 0; off < STRIDE; ++off) {
            const int i0 = base + off, i1 = i0 + STRIDE;
            const float r0 = re[i0], m0 = im[i0], r1 = re[i1], m1 = im[i1];
            re[i0] = c * r0 + s * m1;  im[i0] = c * m0 - s * r1;
            re[i1] = s * m0 + c * r1;  im[i1] = -s * r0 + c * m1;
        }
    }
}

template<int STRIDE>
__device__ __forceinline__ void rz_gate(float re[16], float im[16], float c, float s) {
    // diag(e^{-i t/2}, e^{+i t/2}), c = cos(t/2), s = sin(t/2)
    #pragma unroll
    for (int base = 0; base < 16; base += 2 * STRIDE) {
        #pragma unroll
        for (int off = 0; off < STRIDE; ++off) {
            const int i0 = base + off, i1 = i0 + STRIDE;
            const float r0 = re[i0], m0 = im[i0], r1 = re[i1], m1 = im[i1];
            re[i0] = c * r0 + s * m0;  im[i0] = c * m0 - s * r0;
            re[i1] = c * r1 - s * m1;  im[i1] = s * r1 + c * m1;
        }
    }
}

template<int CMASK, int TMASK>
__device__ __forceinline__ void cnot_gate(float re[16], float im[16]) {
    #pragma unroll
    for (int i = 0; i < 16; ++i) {
        if ((i & CMASK) && !(i & TMASK)) {
            const int j = i | TMASK;
            float t;
            t = re[i]; re[i] = re[j]; re[j] = t;
            t = im[i]; im[i] = im[j]; im[j] = t;
        }
    }
}

// Kernel A: one thread per patch. N = B*196 threads, perfectly wave-balanced
// (401408 = 6272 full waves), no barriers, no LDS, no divergence.
__global__ __launch_bounds__(256) void quanv_feats(
    const float* __restrict__ x,      // (B, 784)
    const float* __restrict__ embW,   // (4, 4) row-major
    const float* __restrict__ embB,   // (4,)
    const float* __restrict__ qp,     // (5,)
    float* __restrict__ feats,        // (B*196, 4)
    int N)                            // B*196
{
    const int gid = blockIdx.x * 256 + threadIdx.x;
    if (gid >= N) return;

    const unsigned b = (unsigned)gid / 196u;
    const unsigned t = (unsigned)gid % 196u;
    const unsigned pi = t / 14u, pj = t % 14u;

    const float* img = x + (size_t)b * 784;
    // Patch: [img[2i,2j], img[2i,2j+1], img[2i+1,2j], img[2i+1,2j+1]]
    const float p0 = img[(2 * pi) * 28 + 2 * pj];
    const float p1 = img[(2 * pi) * 28 + 2 * pj + 1];
    const float p2 = img[(2 * pi + 1) * 28 + 2 * pj];
    const float p3 = img[(2 * pi + 1) * 28 + 2 * pj + 1];

    // Angles: ang[w] = patch . embW[w,:] + embB[w]
    float cA[4], sA[4];
    #pragma unroll
    for (int w = 0; w < 4; ++w) {
        const float a = embB[w] + embW[4 * w + 0] * p0 + embW[4 * w + 1] * p1
                                + embW[4 * w + 2] * p2 + embW[4 * w + 3] * p3;
        __sincosf(0.5f * a, &sA[w], &cA[w]);
    }

    // Fixed-parameter trig (uniform across lanes; cheap).
    float qc[5], qs[5];
    #pragma unroll
    for (int i = 0; i < 5; ++i) __sincosf(0.5f * qp[i], &qs[i], &qc[i]);

    // State after the 4 data RYs: real product state.
    float re[16], im[16];
    #pragma unroll
    for (int idx = 0; idx < 16; ++idx) {
        float v = 1.0f;
        #pragma unroll
        for (int w = 0; w < 4; ++w)
            v *= ((idx >> (3 - w)) & 1) ? sA[w] : cA[w];
        re[idx] = v;
        im[idx] = 0.0f;   // constant-folds through the first tail gate
    }

    // Fixed circuit tail.
    rx_gate<8>(re, im, qc[0], qs[0]);   // RX(q0, wire0)
    ry_gate<4>(re, im, qc[1], qs[1]);   // RY(q1, wire1)
    rz_gate<2>(re, im, qc[2], qs[2]);   // RZ(q2, wire2)
    cnot_gate<8, 4>(re, im);            // CNOT(0,1)
    rx_gate<1>(re, im, qc[3], qs[3]);   // RX(q3, wire3)
    cnot_gate<2, 1>(re, im);            // CNOT(2,3)
    ry_gate<2>(re, im, qc[4], qs[4]);   // RY(q4, wire2)
    cnot_gate<4, 2>(re, im);            // CNOT(1,2)

    // Probabilities.
    float p[16];
    #pragma unroll
    for (int i = 0; i < 16; ++i) p[i] = re[i] * re[i] + im[i] * im[i];

    // Z expectations via partial-sum tree (shares subtotals across wires).
    float a8[8], d8;
    float f0 = 0.0f;
    #pragma unroll
    for (int j = 0; j < 8; ++j) {
        a8[j] = p[j] + p[j + 8];
        f0 += p[j] - p[j + 8];
    }
    float a4[4];
    float f1 = 0.0f;
    #pragma unroll
    for (int j = 0; j < 4; ++j) {
        a4[j] = a8[j] + a8[j + 4];
        f1 += a8[j] - a8[j + 4];
    }
    float a2[2];
    float f2 = 0.0f;
    #pragma unroll
    for (int j = 0; j < 2; ++j) {
        a2[j] = a4[j] + a4[j + 2];
        f2 += a4[j] - a4[j + 2];
    }
    const float f3 = a2[0] - a2[1];
    (void)d8;

    float4 fv;
    fv.x = f0; fv.y = f1; fv.z = f2; fv.w = f3;
    *reinterpret_cast<float4*>(feats + (size_t)gid * 4) = fv;
}

// Kernel B: one block per image — dot feats (784) against linW rows, reduce,
// log_softmax. Validated structure from round 1.
__global__ __launch_bounds__(256) void logits_kernel(
    const float* __restrict__ feats,  // (B, 784) = (B*196, 4)
    const float* __restrict__ linW,   // (10, 784) row-major
    const float* __restrict__ linB,   // (10,)
    float* __restrict__ out)          // (B, 10)
{
    const int b   = blockIdx.x;
    const int tid = threadIdx.x;

    __shared__ float sred[4][10];

    float part[10];
    #pragma unroll
    for (int c = 0; c < 10; ++c) part[c] = 0.0f;

    if (tid < 196) {
        const float4 f = *reinterpret_cast<const float4*>(feats + (size_t)b * 784 + tid * 4);
        #pragma unroll
        for (int c = 0; c < 10; ++c) {
            const float4 wv = *reinterpret_cast<const float4*>(linW + c * 784 + tid * 4);
            part[c] = f.x * wv.x + f.y * wv.y + f.z * wv.z + f.w * wv.w;
        }
    }

    #pragma unroll
    for (int c = 0; c < 10; ++c) {
        part[c] += __shfl_down(part[c], 32);
        part[c] += __shfl_down(part[c], 16);
        part[c] += __shfl_down(part[c], 8);
        part[c] += __shfl_down(part[c], 4);
        part[c] += __shfl_down(part[c], 2);
        part[c] += __shfl_down(part[c], 1);
    }
    const int lane = tid & 63;
    const int wv   = tid >> 6;
    if (lane == 0) {
        #pragma unroll
        for (int c = 0; c < 10; ++c) sred[wv][c] = part[c];
    }
    __syncthreads();

    if (tid == 0) {
        float logit[10];
        float m = -1e30f;
        #pragma unroll
        for (int c = 0; c < 10; ++c) {
            logit[c] = sred[0][c] + sred[1][c] + sred[2][c] + sred[3][c] + linB[c];
            m = fmaxf(m, logit[c]);
        }
        float ssum = 0.0f;
        #pragma unroll
        for (int c = 0; c < 10; ++c) ssum += expf(logit[c] - m);
        const float lse = m + logf(ssum);
        #pragma unroll
        for (int c = 0; c < 10; ++c) out[(size_t)b * 10 + c] = logit[c] - lse;
    }
}

extern "C" void kernel_launch(void* const* d_in, const int* in_sizes, int n_in,
                              void* d_out, int out_size, void* d_ws, size_t ws_size,
                              hipStream_t stream) {
    const float* x    = (const float*)d_in[0];
    const float* embW = (const float*)d_in[1];
    const float* embB = (const float*)d_in[2];
    const float* qp   = (const float*)d_in[3];
    const float* linW = (const float*)d_in[4];
    const float* linB = (const float*)d_in[5];
    float* out   = (float*)d_out;
    float* feats = (float*)d_ws;   // N*4 floats = 6.4 MB, fully overwritten below

    const int B = in_sizes[0] / 784;
    const int N = B * 196;

    quanv_feats<<<(N + 255) / 256, 256, 0, stream>>>(x, embW, embB, qp, feats, N);
    logits_kernel<<<B, 256, 0, stream>>>(feats, linW, linB, out);
}

// Round 3
// 74.819 us; speedup vs baseline: 1.0891x; 1.0891x over previous
//
#include <hip/hip_runtime.h>
#include <hip/hip_bf16.h>

// 4-qubit state: 16 complex amplitudes in registers.
// Index convention (matches reference): wire w is bit (3-w), i.e. wire 0 = MSB (weight 8).

template<int STRIDE>
__device__ __forceinline__ void ry_gate(float re[16], float im[16], float c, float s) {
    #pragma unroll
    for (int base = 0; base < 16; base += 2 * STRIDE) {
        #pragma unroll
        for (int off = 0; off < STRIDE; ++off) {
            const int i0 = base + off, i1 = i0 + STRIDE;
            const float r0 = re[i0], m0 = im[i0], r1 = re[i1], m1 = im[i1];
            re[i0] = c * r0 - s * r1;  im[i0] = c * m0 - s * m1;
            re[i1] = s * r0 + c * r1;  im[i1] = s * m0 + c * m1;
        }
    }
}

template<int STRIDE>
__device__ __forceinline__ void rx_gate(float re[16], float im[16], float c, float s) {
    // [[c, -i s], [-i s, c]]
    #pragma unroll
    for (int base = 0; base < 16; base += 2 * STRIDE) {
        #pragma unroll
        for (int off = 0; off < STRIDE; ++off) {
            const int i0 = base + off, i1 = i0 + STRIDE;
            const float r0 = re[i0], m0 = im[i0], r1 = re[i1], m1 = im[i1];
            re[i0] = c * r0 + s * m1;  im[i0] = c * m0 - s * r1;
            re[i1] = s * m0 + c * r1;  im[i1] = -s * r0 + c * m1;
        }
    }
}

template<int STRIDE>
__device__ __forceinline__ void rz_gate(float re[16], float im[16], float c, float s) {
    // diag(e^{-i t/2}, e^{+i t/2}), c = cos(t/2), s = sin(t/2)
    #pragma unroll
    for (int base = 0; base < 16; base += 2 * STRIDE) {
        #pragma unroll
        for (int off = 0; off < STRIDE; ++off) {
            const int i0 = base + off, i1 = i0 + STRIDE;
            const float r0 = re[i0], m0 = im[i0], r1 = re[i1], m1 = im[i1];
            re[i0] = c * r0 + s * m0;  im[i0] = c * m0 - s * r0;
            re[i1] = c * r1 - s * m1;  im[i1] = s * r1 + c * m1;
        }
    }
}

template<int CMASK, int TMASK>
__device__ __forceinline__ void cnot_gate(float re[16], float im[16]) {
    #pragma unroll
    for (int i = 0; i < 16; ++i) {
        if ((i & CMASK) && !(i & TMASK)) {
            const int j = i | TMASK;
            float t;
            t = re[i]; re[i] = re[j]; re[j] = t;
            t = im[i]; im[i] = im[j]; im[j] = t;
        }
    }
}

// Fused: one block per image. 196 patch-threads run the circuit in registers,
// dot into 10 partial logits, shuffle+LDS reduce, 16-lane-parallel log_softmax.
// No ws traffic, single launch (round-2 split regressed: launch+serialization
// +12.8MB ws round-trip cost more than the wave-imbalance it fixed).
__global__ __launch_bounds__(256) void quanv_fused(
    const float* __restrict__ x,      // (B, 784)
    const float* __restrict__ embW,   // (4, 4) row-major
    const float* __restrict__ embB,   // (4,)
    const float* __restrict__ qp,     // (5,)
    const float* __restrict__ linW,   // (10, 784) row-major
    const float* __restrict__ linB,   // (10,)
    float* __restrict__ out)          // (B, 10)
{
    const int b   = blockIdx.x;
    const int tid = threadIdx.x;

    __shared__ float sred[4][10];

    float part[10];
    #pragma unroll
    for (int c = 0; c < 10; ++c) part[c] = 0.0f;

    if (tid < 196) {
        const unsigned pi = (unsigned)tid / 14u, pj = (unsigned)tid % 14u;
        const float* img = x + (size_t)b * 784;
        // 2x2 patch as two aligned float2 loads (byte offset is 8-aligned: even*4).
        const float2 r0 = *reinterpret_cast<const float2*>(img + (2 * pi) * 28 + 2 * pj);
        const float2 r1 = *reinterpret_cast<const float2*>(img + (2 * pi + 1) * 28 + 2 * pj);
        const float p0 = r0.x, p1 = r0.y, p2 = r1.x, p3 = r1.y;

        // Angles: ang[w] = patch . embW[w,:] + embB[w]
        float cA[4], sA[4];
        #pragma unroll
        for (int w = 0; w < 4; ++w) {
            const float a = embB[w] + embW[4 * w + 0] * p0 + embW[4 * w + 1] * p1
                                    + embW[4 * w + 2] * p2 + embW[4 * w + 3] * p3;
            __sincosf(0.5f * a, &sA[w], &cA[w]);
        }

        // Fixed-parameter trig (uniform across lanes; cheap).
        float qc[5], qs[5];
        #pragma unroll
        for (int i = 0; i < 5; ++i) __sincosf(0.5f * qp[i], &qs[i], &qc[i]);

        // State after the 4 data RYs: real product state, built as a 28-mult tree.
        // idx bits (MSB..LSB) = wires 0..3.
        float re[16], im[16];
        float ab[4], abc[8];
        ab[0] = cA[0] * cA[1];  ab[1] = cA[0] * sA[1];
        ab[2] = sA[0] * cA[1];  ab[3] = sA[0] * sA[1];
        #pragma unroll
        for (int j = 0; j < 4; ++j) {
            abc[2 * j]     = ab[j] * cA[2];
            abc[2 * j + 1] = ab[j] * sA[2];
        }
        #pragma unroll
        for (int k = 0; k < 8; ++k) {
            re[2 * k]     = abc[k] * cA[3];
            re[2 * k + 1] = abc[k] * sA[3];
            im[2 * k] = 0.0f;  im[2 * k + 1] = 0.0f;  // folds through first gate
        }

        // Fixed circuit tail.
        rx_gate<8>(re, im, qc[0], qs[0]);   // RX(q0, wire0)
        ry_gate<4>(re, im, qc[1], qs[1]);   // RY(q1, wire1)
        rz_gate<2>(re, im, qc[2], qs[2]);   // RZ(q2, wire2)
        cnot_gate<8, 4>(re, im);            // CNOT(0,1)
        rx_gate<1>(re, im, qc[3], qs[3]);   // RX(q3, wire3)
        cnot_gate<2, 1>(re, im);            // CNOT(2,3)
        ry_gate<2>(re, im, qc[4], qs[4]);   // RY(q4, wire2)
        cnot_gate<4, 2>(re, im);            // CNOT(1,2)

        // Probabilities.
        float p[16];
        #pragma unroll
        for (int i = 0; i < 16; ++i) p[i] = re[i] * re[i] + im[i] * im[i];

        // Z expectations via shared partial-sum tree.
        float a8[8], a4[4], a2[2];
        float f0 = 0.0f, f1 = 0.0f, f2 = 0.0f;
        #pragma unroll
        for (int j = 0; j < 8; ++j) { a8[j] = p[j] + p[j + 8]; f0 += p[j] - p[j + 8]; }
        #pragma unroll
        for (int j = 0; j < 4; ++j) { a4[j] = a8[j] + a8[j + 4]; f1 += a8[j] - a8[j + 4]; }
        #pragma unroll
        for (int j = 0; j < 2; ++j) { a2[j] = a4[j] + a4[j + 2]; f2 += a4[j] - a4[j + 2]; }
        const float f3 = a2[0] - a2[1];

        // Partial logits against coalesced float4 slice of linW (L2-resident, 31 KB).
        #pragma unroll
        for (int c = 0; c < 10; ++c) {
            const float4 wv = *reinterpret_cast<const float4*>(linW + c * 784 + tid * 4);
            part[c] = f0 * wv.x + f1 * wv.y + f2 * wv.z + f3 * wv.w;
        }
    }

    // Wave (64-lane) shuffle reduction, then cross-wave via LDS.
    #pragma unroll
    for (int c = 0; c < 10; ++c) {
        part[c] += __shfl_down(part[c], 32);
        part[c] += __shfl_down(part[c], 16);
        part[c] += __shfl_down(part[c], 8);
        part[c] += __shfl_down(part[c], 4);
        part[c] += __shfl_down(part[c], 2);
        part[c] += __shfl_down(part[c], 1);
    }
    const int lane = tid & 63;
    const int wv   = tid >> 6;
    if (lane == 0) {
        #pragma unroll
        for (int c = 0; c < 10; ++c) sred[wv][c] = part[c];
    }
    __syncthreads();

    // log_softmax across 10 classes, parallel over the first 16 lanes.
    if (tid < 16) {
        float logit = -1e30f;
        if (tid < 10)
            logit = sred[0][tid] + sred[1][tid] + sred[2][tid] + sred[3][tid] + linB[tid];
        float m = logit;
        m = fmaxf(m, __shfl_xor(m, 1, 16));
        m = fmaxf(m, __shfl_xor(m, 2, 16));
        m = fmaxf(m, __shfl_xor(m, 4, 16));
        m = fmaxf(m, __shfl_xor(m, 8, 16));
        float e = (tid < 10) ? expf(logit - m) : 0.0f;
        e += __shfl_xor(e, 1, 16);
        e += __shfl_xor(e, 2, 16);
        e += __shfl_xor(e, 4, 16);
        e += __shfl_xor(e, 8, 16);
        const float lse = m + logf(e);
        if (tid < 10) out[(size_t)b * 10 + tid] = logit - lse;
    }
}

extern "C" void kernel_launch(void* const* d_in, const int* in_sizes, int n_in,
                              void* d_out, int out_size, void* d_ws, size_t ws_size,
                              hipStream_t stream) {
    const float* x    = (const float*)d_in[0];
    const float* embW = (const float*)d_in[1];
    const float* embB = (const float*)d_in[2];
    const float* qp   = (const float*)d_in[3];
    const float* linW = (const float*)d_in[4];
    const float* linB = (const float*)d_in[5];
    float* out = (float*)d_out;

    const int B = in_sizes[0] / 784;
    quanv_fused<<<B, 256, 0, stream>>>(x, embW, embB, qp, linW, linB, out);
}

// Round 4
// 74.699 us; speedup vs baseline: 1.0908x; 1.0016x over previous
//
#include <hip/hip_runtime.h>
#include <hip/hip_bf16.h>

// 4-qubit state: 16 complex amplitudes in registers.
// Index convention (matches reference): wire w is bit (3-w), i.e. wire 0 = MSB (weight 8).

template<int STRIDE>
__device__ __forceinline__ void ry_gate(float re[16], float im[16], float c, float s) {
    #pragma unroll
    for (int base = 0; base < 16; base += 2 * STRIDE) {
        #pragma unroll
        for (int off = 0; off < STRIDE; ++off) {
            const int i0 = base + off, i1 = i0 + STRIDE;
            const float r0 = re[i0], m0 = im[i0], r1 = re[i1], m1 = im[i1];
            re[i0] = c * r0 - s * r1;  im[i0] = c * m0 - s * m1;
            re[i1] = s * r0 + c * r1;  im[i1] = s * m0 + c * m1;
        }
    }
}

template<int STRIDE>
__device__ __forceinline__ void rx_gate(float re[16], float im[16], float c, float s) {
    // [[c, -i s], [-i s, c]]
    #pragma unroll
    for (int base = 0; base < 16; base += 2 * STRIDE) {
        #pragma unroll
        for (int off = 0; off < STRIDE; ++off) {
            const int i0 = base + off, i1 = i0 + STRIDE;
            const float r0 = re[i0], m0 = im[i0], r1 = re[i1], m1 = im[i1];
            re[i0] = c * r0 + s * m1;  im[i0] = c * m0 - s * r1;
            re[i1] = s * m0 + c * r1;  im[i1] = -s * r0 + c * m1;
        }
    }
}

template<int STRIDE>
__device__ __forceinline__ void rz_gate(float re[16], float im[16], float c, float s) {
    // diag(e^{-i t/2}, e^{+i t/2}), c = cos(t/2), s = sin(t/2)
    #pragma unroll
    for (int base = 0; base < 16; base += 2 * STRIDE) {
        #pragma unroll
        for (int off = 0; off < STRIDE; ++off) {
            const int i0 = base + off, i1 = i0 + STRIDE;
            const float r0 = re[i0], m0 = im[i0], r1 = re[i1], m1 = im[i1];
            re[i0] = c * r0 + s * m0;  im[i0] = c * m0 - s * r0;
            re[i1] = c * r1 - s * m1;  im[i1] = s * r1 + c * m1;
        }
    }
}

template<int CMASK, int TMASK>
__device__ __forceinline__ void cnot_gate(float re[16], float im[16]) {
    #pragma unroll
    for (int i = 0; i < 16; ++i) {
        if ((i & CMASK) && !(i & TMASK)) {
            const int j = i | TMASK;
            float t;
            t = re[i]; re[i] = re[j]; re[j] = t;
            t = im[i]; im[i] = im[j]; im[j] = t;
        }
    }
}

// Fused: one block per image.
// Phase 1: 196 patch-threads run the circuit in registers -> feats float4 -> LDS.
// Phase 2: 160 threads (10 ch x 16) dot feats vs linW with a 4-level 16-lane
//          xor-shuffle reduce (wave-level DS ops/block ~240 -> ~60 vs the old
//          10ch x 6-level all-wave shuffle tree, which was the DS-pipe hot spot).
// Phase 3: 16-lane parallel log_softmax.
__global__ __launch_bounds__(256) void quanv_fused(
    const float* __restrict__ x,      // (B, 784)
    const float* __restrict__ embW,   // (4, 4) row-major
    const float* __restrict__ embB,   // (4,)
    const float* __restrict__ qp,     // (5,)
    const float* __restrict__ linW,   // (10, 784) row-major
    const float* __restrict__ linB,   // (10,)
    float* __restrict__ out)          // (B, 10)
{
    const int b   = blockIdx.x;
    const int tid = threadIdx.x;

    __shared__ float4 sfeats[196];   // feats per patch; reads are broadcast/2-way (free)
    __shared__ float  slog[10];

    if (tid < 196) {
        const unsigned pi = (unsigned)tid / 14u, pj = (unsigned)tid % 14u;
        const float* img = x + (size_t)b * 784;
        // 2x2 patch as two aligned float2 loads (byte offset is 8-aligned: even*4).
        const float2 r0 = *reinterpret_cast<const float2*>(img + (2 * pi) * 28 + 2 * pj);
        const float2 r1 = *reinterpret_cast<const float2*>(img + (2 * pi + 1) * 28 + 2 * pj);
        const float p0 = r0.x, p1 = r0.y, p2 = r1.x, p3 = r1.y;

        // Angles: ang[w] = patch . embW[w,:] + embB[w]
        float cA[4], sA[4];
        #pragma unroll
        for (int w = 0; w < 4; ++w) {
            const float a = embB[w] + embW[4 * w + 0] * p0 + embW[4 * w + 1] * p1
                                    + embW[4 * w + 2] * p2 + embW[4 * w + 3] * p3;
            __sincosf(0.5f * a, &sA[w], &cA[w]);
        }

        // Fixed-parameter trig (uniform across lanes).
        float qc[5], qs[5];
        #pragma unroll
        for (int i = 0; i < 5; ++i) __sincosf(0.5f * qp[i], &qs[i], &qc[i]);

        // State after the 4 data RYs: real product state, 28-mult tree.
        float re[16], im[16];
        float ab[4], abc[8];
        ab[0] = cA[0] * cA[1];  ab[1] = cA[0] * sA[1];
        ab[2] = sA[0] * cA[1];  ab[3] = sA[0] * sA[1];
        #pragma unroll
        for (int j = 0; j < 4; ++j) {
            abc[2 * j]     = ab[j] * cA[2];
            abc[2 * j + 1] = ab[j] * sA[2];
        }
        #pragma unroll
        for (int k = 0; k < 8; ++k) {
            re[2 * k]     = abc[k] * cA[3];
            re[2 * k + 1] = abc[k] * sA[3];
        }

        // RX(q0, wire0) specialized for im == 0 input (compiler can't fold s*0.0f
        // without fast-math): 32 muls instead of 64 ops.
        {
            const float c = qc[0], s = qs[0];
            #pragma unroll
            for (int i0 = 0; i0 < 8; ++i0) {
                const int i1 = i0 + 8;
                const float r0 = re[i0], r1 = re[i1];
                re[i0] = c * r0;   im[i0] = -s * r1;
                re[i1] = c * r1;   im[i1] = -s * r0;
            }
        }

        // Remaining fixed circuit tail.
        ry_gate<4>(re, im, qc[1], qs[1]);   // RY(q1, wire1)
        rz_gate<2>(re, im, qc[2], qs[2]);   // RZ(q2, wire2)
        cnot_gate<8, 4>(re, im);            // CNOT(0,1)
        rx_gate<1>(re, im, qc[3], qs[3]);   // RX(q3, wire3)
        cnot_gate<2, 1>(re, im);            // CNOT(2,3)
        ry_gate<2>(re, im, qc[4], qs[4]);   // RY(q4, wire2)
        cnot_gate<4, 2>(re, im);            // CNOT(1,2)

        // Probabilities.
        float p[16];
        #pragma unroll
        for (int i = 0; i < 16; ++i) p[i] = re[i] * re[i] + im[i] * im[i];

        // Z expectations via shared partial-sum tree.
        float a8[8], a4[4], a2[2];
        float f0 = 0.0f, f1 = 0.0f, f2 = 0.0f;
        #pragma unroll
        for (int j = 0; j < 8; ++j) { a8[j] = p[j] + p[j + 8]; f0 += p[j] - p[j + 8]; }
        #pragma unroll
        for (int j = 0; j < 4; ++j) { a4[j] = a8[j] + a8[j + 4]; f1 += a8[j] - a8[j + 4]; }
        #pragma unroll
        for (int j = 0; j < 2; ++j) { a2[j] = a4[j] + a4[j + 2]; f2 += a4[j] - a4[j + 2]; }
        const float f3 = a2[0] - a2[1];

        sfeats[tid] = make_float4(f0, f1, f2, f3);
    }
    __syncthreads();

    // Channel-split dot + reduce: thread (c, j) handles channel c, patches j::16.
    if (tid < 160) {
        const int c = tid >> 4;
        const int j = tid & 15;
        float acc = 0.0f;
        for (int p = j; p < 196; p += 16) {
            const float4 f  = sfeats[p];
            const float4 wv = *reinterpret_cast<const float4*>(linW + c * 784 + p * 4);
            acc += f.x * wv.x + f.y * wv.y + f.z * wv.z + f.w * wv.w;
        }
        // 16-lane group reduce (groups are 16-aligned; xor stays in-group).
        acc += __shfl_xor(acc, 8);
        acc += __shfl_xor(acc, 4);
        acc += __shfl_xor(acc, 2);
        acc += __shfl_xor(acc, 1);
        if (j == 0) slog[c] = acc;
    }
    __syncthreads();

    // log_softmax across 10 classes, parallel over the first 16 lanes.
    if (tid < 16) {
        const float logit = (tid < 10) ? (slog[tid] + linB[tid]) : -1e30f;
        float m = logit;
        m = fmaxf(m, __shfl_xor(m, 1, 16));
        m = fmaxf(m, __shfl_xor(m, 2, 16));
        m = fmaxf(m, __shfl_xor(m, 4, 16));
        m = fmaxf(m, __shfl_xor(m, 8, 16));
        float e = (tid < 10) ? expf(logit - m) : 0.0f;
        e += __shfl_xor(e, 1, 16);
        e += __shfl_xor(e, 2, 16);
        e += __shfl_xor(e, 4, 16);
        e += __shfl_xor(e, 8, 16);
        const float lse = m + logf(e);
        if (tid < 10) out[(size_t)b * 10 + tid] = logit - lse;
    }
}

extern "C" void kernel_launch(void* const* d_in, const int* in_sizes, int n_in,
                              void* d_out, int out_size, void* d_ws, size_t ws_size,
                              hipStream_t stream) {
    const float* x    = (const float*)d_in[0];
    const float* embW = (const float*)d_in[1];
    const float* embB = (const float*)d_in[2];
    const float* qp   = (const float*)d_in[3];
    const float* linW = (const float*)d_in[4];
    const float* linB = (const float*)d_in[5];
    float* out = (float*)d_out;

    const int B = in_sizes[0] / 784;
    quanv_fused<<<B, 256, 0, stream>>>(x, embW, embB, qp, linW, linB, out);
}